// Round 4
// baseline (272.670 us; speedup 1.0000x reference)
//
#include <hip/hip_runtime.h>
#include <hip/hip_fp16.h>

#define IN_F  64
#define MID_F 128
#define OUT_F 32
#define SEGS_PER_BLK 64

typedef __bf16 bf16x8 __attribute__((ext_vector_type(8)));
typedef float  f32x4  __attribute__((ext_vector_type(4)));

static __device__ inline unsigned pack2(float a, float b) {
    unsigned short x = __builtin_bit_cast(unsigned short, (__bf16)a);
    unsigned short y = __builtin_bit_cast(unsigned short, (__bf16)b);
    return (unsigned)x | ((unsigned)y << 16);
}
static __device__ inline unsigned pkh2(float a, float b) {
    __half2 h = __floats2half2_rn(a, b);
    return __builtin_bit_cast(unsigned, h);
}

// ---------------- CSR build ----------------
__global__ void hist_rank_kernel(const int* __restrict__ sidx, unsigned* __restrict__ counts,
                                 unsigned* __restrict__ ranks, int n) {
    int i = blockIdx.x * blockDim.x + threadIdx.x;
    int stride = gridDim.x * blockDim.x;
    for (; i < n; i += stride) ranks[i] = atomicAdd(&counts[sidx[i]], 1u);
}

__global__ void scan1_kernel(const unsigned* __restrict__ counts, unsigned* __restrict__ offsets,
                             unsigned* __restrict__ bsum, int nsegP) {
    __shared__ unsigned s[1024];
    const int t = threadIdx.x;
    const int idx = blockIdx.x * 1024 + t;
    unsigned v = (idx < nsegP) ? counts[idx] : 0u;
    s[t] = v; __syncthreads();
    for (int o = 1; o < 1024; o <<= 1) {
        unsigned u = (t >= o) ? s[t - o] : 0u;
        __syncthreads();
        s[t] += u;
        __syncthreads();
    }
    if (idx < nsegP) offsets[idx] = s[t] - v;       // exclusive
    if (t == 1023) bsum[blockIdx.x] = s[1023];      // block total
}

// block 0: scan of block sums. block 1: build fragment-ordered bf16 weights.
__global__ void scan2_prep_kernel(unsigned* __restrict__ bsum, int nb,
                                  const float* __restrict__ W1,
                                  const float* __restrict__ W2,
                                  unsigned* __restrict__ wbuf /* int4-granular */) {
    const int t = threadIdx.x;
    if (blockIdx.x == 0) {
        __shared__ unsigned s[1024];
        unsigned v = (t < nb) ? bsum[t] : 0u;
        s[t] = v; __syncthreads();
        for (int o = 1; o < 1024; o <<= 1) {
            unsigned u = (t >= o) ? s[t - o] : 0u;
            __syncthreads();
            s[t] += u;
            __syncthreads();
        }
        if (t < nb) bsum[t] = s[t] - v;             // exclusive, in place
        return;
    }
    // --- weight prep ---
    // w1frag: 1024 int4 at wbuf[0..16KB). item i: f=i>>6 (t1=f>>1,q=f&1), l=i&63.
    // elem j (0..7): W1[(q*32+lg*8+j)*MID_F + (t1*16+lr)]
    if (t < 1024) {
        const int i = t;
        const int f = i >> 6, l = i & 63;
        const int t1 = f >> 1, q = f & 1, lg = l >> 4, lr = l & 15;
        unsigned r[4];
        #pragma unroll
        for (int jj = 0; jj < 4; ++jj) {
            const int k0 = q * 32 + lg * 8 + 2 * jj;
            const float v0 = W1[(size_t)k0 * MID_F + t1 * 16 + lr];
            const float v1 = W1[(size_t)(k0 + 1) * MID_F + t1 * 16 + lr];
            r[jj] = pack2(v0, v1);
        }
        ((uint4*)wbuf)[i] = make_uint4(r[0], r[1], r[2], r[3]);
    }
    // w2frag: 512 int4 at wbuf[16KB..24KB). item i: f=i>>6 (u=f>>2,q2=f&3), l=i&63.
    // elem j: k = q2*32 + 16*(j>>2) + lg*4 + (j&3); col = perm(u*16+lr).
    if (t < 512) {
        const int i = t;
        const int f = i >> 6, l = i & 63;
        const int u = f >> 2, q2 = f & 3, lg = l >> 4, lr = l & 15;
        const int n = u * 16 + lr;
        const int pn = ((n >> 2) & 3) * 8 + (n >> 4) * 4 + (n & 3);
        unsigned r[4];
        #pragma unroll
        for (int jj = 0; jj < 4; ++jj) {
            const int j0 = 2 * jj, j1 = 2 * jj + 1;
            const int ka = q2 * 32 + 16 * (j0 >> 2) + lg * 4 + (j0 & 3);
            const int kb = q2 * 32 + 16 * (j1 >> 2) + lg * 4 + (j1 & 3);
            r[jj] = pack2(W2[(size_t)ka * OUT_F + pn], W2[(size_t)kb * OUT_F + pn]);
        }
        ((uint4*)wbuf)[1024 + i] = make_uint4(r[0], r[1], r[2], r[3]);
    }
}

__global__ void scan3_kernel(unsigned* __restrict__ offsets, const unsigned* __restrict__ bsum,
                             int nsegP, int nrows) {
    int idx = blockIdx.x * 1024 + threadIdx.x;
    if (idx < nsegP) offsets[idx] += bsum[blockIdx.x];
    if (blockIdx.x == 0 && threadIdx.x == 0) offsets[nsegP] = (unsigned)nrows;
}

// pos[i] = offsets[sidx[i]] + ranks[i]  (in place over ranks)
__global__ void pos_kernel(const int* __restrict__ sidx, const unsigned* __restrict__ offsets,
                           unsigned* __restrict__ ranks, int n) {
    int i = blockIdx.x * blockDim.x + threadIdx.x;
    int stride = gridDim.x * blockDim.x;
    for (; i < n; i += stride) ranks[i] = offsets[sidx[i]] + ranks[i];
}

// ---------------- streaming MLP -> scatter preds to sorted slot ----------------
// Fragment-ordered weights in LDS: read as ds_read_b128 at ((frag*64+lane)*16)
// -> consecutive lanes hit consecutive 16B -> conflict-free.
__global__ __launch_bounds__(256, 4) void mlp_pred_kernel(
    const float* __restrict__ vecs,
    const unsigned* __restrict__ pos,
    const unsigned* __restrict__ wbuf,
    const float* __restrict__ b1, const float* __restrict__ b2,
    __half* __restrict__ preds, int nrows)
{
    __shared__ __align__(16) __bf16 sW1F[16 * 64 * 8];   // 16 KB frag-ordered
    __shared__ __align__(16) __bf16 sW2F[8 * 64 * 8];    //  8 KB frag-ordered
    __shared__ __align__(16) float sB1[MID_F];
    __shared__ __align__(16) float sB2[OUT_F];

    const int tid = threadIdx.x;
    {   // linear 24 KB copy, coalesced, conflict-free
        const uint4* src = (const uint4*)wbuf;
        uint4* d1 = (uint4*)sW1F;
        uint4* d2 = (uint4*)sW2F;
        #pragma unroll
        for (int i = tid; i < 1024; i += 256) d1[i] = src[i];
        #pragma unroll
        for (int i = tid; i < 512; i += 256) d2[i] = src[1024 + i];
        if (tid < MID_F) sB1[tid] = b1[tid];
        if (tid < OUT_F) sB2[tid] = b2[tid];
    }
    __syncthreads();

    const int lane = tid & 63, wid = tid >> 6;
    const int lg = lane >> 4;

    const int nchunk = nrows >> 4;
    for (int c = blockIdx.x * 4 + wid; c < nchunk; c += gridDim.x * 4) {
        const int base = c << 4;
        const int myrow = base + (lane & 15);

        // Coalesced x tile load (consecutive rows), convert to bf16 A-frags.
        const float* xr = vecs + (size_t)myrow * IN_F + lg * 8;
        f32x4 x0a = *(const f32x4*)(xr);
        f32x4 x0b = *(const f32x4*)(xr + 4);
        f32x4 x1a = *(const f32x4*)(xr + 32);
        f32x4 x1b = *(const f32x4*)(xr + 36);
        const unsigned dst = pos[myrow];
        bf16x8 a[2];
        #pragma unroll
        for (int j = 0; j < 4; ++j) {
            a[0][j] = (__bf16)x0a[j]; a[0][j + 4] = (__bf16)x0b[j];
            a[1][j] = (__bf16)x1a[j]; a[1][j + 4] = (__bf16)x1b[j];
        }

        // Layer 1 (swapped): lane owns h[row lr][feat t*16+lg*4+r].
        unsigned p[8][2];
        #pragma unroll
        for (int t = 0; t < 8; ++t) {
            bf16x8 w1a = *(const bf16x8*)&sW1F[((t * 2 + 0) * 64 + lane) * 8];
            bf16x8 w1b = *(const bf16x8*)&sW1F[((t * 2 + 1) * 64 + lane) * 8];
            f32x4 acc = *(const f32x4*)&sB1[t * 16 + lg * 4];
            acc = __builtin_amdgcn_mfma_f32_16x16x32_bf16(w1a, a[0], acc, 0, 0, 0);
            acc = __builtin_amdgcn_mfma_f32_16x16x32_bf16(w1b, a[1], acc, 0, 0, 0);
            p[t][0] = pack2(fmaxf(acc[0], 0.f), fmaxf(acc[1], 0.f));
            p[t][1] = pack2(fmaxf(acc[2], 0.f), fmaxf(acc[3], 0.f));
        }

        // Layer 2 (swapped, zero-shuffle; lane's own packed h tiles are B).
        f32x4 acc2[2];
        acc2[0] = *(const f32x4*)&sB2[lg * 8];
        acc2[1] = *(const f32x4*)&sB2[lg * 8 + 4];
        #pragma unroll
        for (int q = 0; q < 4; ++q) {
            uint4 bi = make_uint4(p[2 * q][0], p[2 * q][1], p[2 * q + 1][0], p[2 * q + 1][1]);
            bf16x8 B = __builtin_bit_cast(bf16x8, bi);
            bf16x8 w2a = *(const bf16x8*)&sW2F[((0 * 4 + q) * 64 + lane) * 8];
            bf16x8 w2b = *(const bf16x8*)&sW2F[((1 * 4 + q) * 64 + lane) * 8];
            acc2[0] = __builtin_amdgcn_mfma_f32_16x16x32_bf16(w2a, B, acc2[0], 0, 0, 0);
            acc2[1] = __builtin_amdgcn_mfma_f32_16x16x32_bf16(w2b, B, acc2[1], 0, 0, 0);
        }

        // One 16B store per lane; 4 lanes complete the row's 64B line.
        uint4 st = make_uint4(pkh2(acc2[0][0], acc2[0][1]), pkh2(acc2[0][2], acc2[0][3]),
                              pkh2(acc2[1][0], acc2[1][1]), pkh2(acc2[1][2], acc2[1][3]));
        *(uint4*)(preds + (size_t)dst * OUT_F + lg * 8) = st;
    }
}

// ---------------- coalesced segment mean ----------------
__global__ __launch_bounds__(256) void seg_reduce_kernel(
    const __half* __restrict__ preds,
    const unsigned* __restrict__ offsets,
    float* __restrict__ out, int nseg)
{
    const int tid = threadIdx.x;
    const int lane = tid & 63, wid = tid >> 6;
    const int fp = lane & 15;   // feature pair 0..15
    const int ro = lane >> 4;   // row offset 0..3

    for (int s = wid; s < SEGS_PER_BLK; s += 4) {
        const int gs = blockIdx.x * SEGS_PER_BLK + s;
        if (gs >= nseg) continue;
        const unsigned o0 = offsets[gs], o1 = offsets[gs + 1];

        float a0 = 0.f, a1 = 0.f;
        for (unsigned r = o0 + ro; r < o1; r += 4) {
            __half2 h = *(const __half2*)(preds + (size_t)r * OUT_F + fp * 2);
            float2 f = __half22float2(h);
            a0 += f.x; a1 += f.y;
        }
        a0 += __shfl_xor(a0, 16); a1 += __shfl_xor(a1, 16);
        a0 += __shfl_xor(a0, 32); a1 += __shfl_xor(a1, 32);
        if (lane < 16) {
            const float inv = 1.f / fmaxf((float)(o1 - o0), 1.f);
            *(float2*)(out + (size_t)gs * OUT_F + fp * 2) = make_float2(a0 * inv, a1 * inv);
        }
    }
}

// ---------------- fallback (direct global atomics, round-1 proven) ----------------
typedef __bf16 bf16x4 __attribute__((ext_vector_type(4)));
__global__ __launch_bounds__(256) void fb_mlp_scatter(
    const float* __restrict__ vecs, const int* __restrict__ sidx,
    const float* __restrict__ W1, const float* __restrict__ b1,
    const float* __restrict__ W2, const float* __restrict__ b2,
    float* __restrict__ osum, float* __restrict__ counts, int nrows)
{
    __shared__ __align__(16) __bf16 sW1T[MID_F][IN_F];
    __shared__ __align__(16) __bf16 sW2T[OUT_F][MID_F];
    const int tid = threadIdx.x;
    for (int i = tid; i < IN_F * MID_F; i += 256)
        sW1T[i & (MID_F - 1)][i >> 7] = (__bf16)W1[i];
    for (int i = tid; i < MID_F * OUT_F; i += 256)
        sW2T[i & (OUT_F - 1)][i >> 5] = (__bf16)W2[i];
    __syncthreads();
    const int lane = tid & 63, wid = tid >> 6, lg = lane >> 4, lr = lane & 15;
    bf16x8 w1f[8][2];
    for (int t = 0; t < 8; ++t)
        for (int q = 0; q < 2; ++q)
            w1f[t][q] = *(const bf16x8*)&sW1T[t * 16 + lr][q * 32 + lg * 8];
    bf16x8 w2f[2][4];
    for (int u = 0; u < 2; ++u)
        for (int q = 0; q < 4; ++q) {
            bf16x4 lo = *(const bf16x4*)&sW2T[u * 16 + lr][q * 32 + lg * 4];
            bf16x4 hi = *(const bf16x4*)&sW2T[u * 16 + lr][q * 32 + 16 + lg * 4];
            w2f[u][q] = __builtin_shufflevector(lo, hi, 0, 1, 2, 3, 4, 5, 6, 7);
        }
    float b1v[8][4], b2v[2][4];
    for (int t = 0; t < 8; ++t)
        for (int r = 0; r < 4; ++r) b1v[t][r] = b1[t * 16 + lg * 4 + r];
    for (int u = 0; u < 2; ++u)
        for (int r = 0; r < 4; ++r) b2v[u][r] = b2[u * 16 + lg * 4 + r];
    const int nchunk = nrows >> 4;
    for (int c = blockIdx.x * 4 + wid; c < nchunk; c += gridDim.x * 4) {
        const int base = c << 4, myrow = base + lr;
        const float* xr = vecs + (size_t)myrow * IN_F + lg * 8;
        f32x4 x0a = *(const f32x4*)(xr), x0b = *(const f32x4*)(xr + 4);
        f32x4 x1a = *(const f32x4*)(xr + 32), x1b = *(const f32x4*)(xr + 36);
        bf16x8 a[2];
        for (int j = 0; j < 4; ++j) {
            a[0][j] = (__bf16)x0a[j]; a[0][j + 4] = (__bf16)x0b[j];
            a[1][j] = (__bf16)x1a[j]; a[1][j + 4] = (__bf16)x1b[j];
        }
        unsigned p[8][2];
        for (int t = 0; t < 8; ++t) {
            f32x4 acc = { b1v[t][0], b1v[t][1], b1v[t][2], b1v[t][3] };
            acc = __builtin_amdgcn_mfma_f32_16x16x32_bf16(w1f[t][0], a[0], acc, 0, 0, 0);
            acc = __builtin_amdgcn_mfma_f32_16x16x32_bf16(w1f[t][1], a[1], acc, 0, 0, 0);
            p[t][0] = pack2(fmaxf(acc[0], 0.f), fmaxf(acc[1], 0.f));
            p[t][1] = pack2(fmaxf(acc[2], 0.f), fmaxf(acc[3], 0.f));
        }
        f32x4 acc2[2];
        acc2[0] = { b2v[0][0], b2v[0][1], b2v[0][2], b2v[0][3] };
        acc2[1] = { b2v[1][0], b2v[1][1], b2v[1][2], b2v[1][3] };
        for (int q = 0; q < 4; ++q) {
            uint4 bi = make_uint4(p[2 * q][0], p[2 * q][1], p[2 * q + 1][0], p[2 * q + 1][1]);
            bf16x8 B = __builtin_bit_cast(bf16x8, bi);
            acc2[0] = __builtin_amdgcn_mfma_f32_16x16x32_bf16(w2f[0][q], B, acc2[0], 0, 0, 0);
            acc2[1] = __builtin_amdgcn_mfma_f32_16x16x32_bf16(w2f[1][q], B, acc2[1], 0, 0, 0);
        }
        const int seg = sidx[myrow];
        float* o = osum + (size_t)seg * OUT_F;
        for (int u = 0; u < 2; ++u)
            for (int r = 0; r < 4; ++r)
                atomicAdd(o + u * 16 + lg * 4 + r, acc2[u][r]);
        if (lg == 0) atomicAdd(counts + seg, 1.0f);
    }
}

__global__ __launch_bounds__(256) void fb_finalize(
    float* __restrict__ osum, const float* __restrict__ counts, int total)
{
    int i = blockIdx.x * 256 + threadIdx.x;
    if (i < total) osum[i] = osum[i] / fmaxf(counts[i >> 5], 1.0f);
}

extern "C" void kernel_launch(void* const* d_in, const int* in_sizes, int n_in,
                              void* d_out, int out_size, void* d_ws, size_t ws_size,
                              hipStream_t stream)
{
    const float* vecs = (const float*)d_in[0];
    const int*   sidx = (const int*)d_in[1];
    const float* W1 = (const float*)d_in[3];
    const float* b1 = (const float*)d_in[4];
    const float* W2 = (const float*)d_in[5];
    const float* b2 = (const float*)d_in[6];
    float* out = (float*)d_out;

    const int nrows = in_sizes[0] / IN_F;
    const int nseg  = out_size / OUT_F;
    const int nblk  = (nseg + SEGS_PER_BLK - 1) / SEGS_PER_BLK;
    const int nsegP = nblk * SEGS_PER_BLK;
    const int nsb   = (nsegP + 1023) / 1024;   // <= 1024 assumed

    auto algn = [](size_t x) { return (x + 255) & ~(size_t)255; };
    size_t off_counts = 0;
    size_t off_offs   = off_counts + algn((size_t)nsegP * 4);
    size_t off_bsum   = off_offs   + algn((size_t)(nsegP + 1) * 4);
    size_t off_wbuf   = off_bsum   + algn(1024 * 4);
    size_t off_ranks  = off_wbuf   + algn(24 * 1024);
    size_t off_preds  = off_ranks  + algn((size_t)nrows * 4);
    size_t need       = off_preds  + (size_t)nrows * OUT_F * sizeof(__half);

    if (ws_size < need) {
        float* osum   = out;
        float* counts = (float*)d_ws;
        hipMemsetAsync(osum, 0, (size_t)out_size * sizeof(float), stream);
        hipMemsetAsync(counts, 0, (size_t)nseg * sizeof(float), stream);
        fb_mlp_scatter<<<2048, 256, 0, stream>>>(vecs, sidx, W1, b1, W2, b2,
                                                 osum, counts, nrows);
        fb_finalize<<<(out_size + 255) / 256, 256, 0, stream>>>(osum, counts, out_size);
        return;
    }

    char* w = (char*)d_ws;
    unsigned* counts  = (unsigned*)(w + off_counts);
    unsigned* offsets = (unsigned*)(w + off_offs);
    unsigned* bsum    = (unsigned*)(w + off_bsum);
    unsigned* wbuf    = (unsigned*)(w + off_wbuf);
    unsigned* ranks   = (unsigned*)(w + off_ranks);   // becomes pos[] after pos_kernel
    __half*   preds   = (__half*)(w + off_preds);

    hipMemsetAsync(counts, 0, (size_t)nsegP * 4, stream);
    hist_rank_kernel<<<2048, 256, 0, stream>>>(sidx, counts, ranks, nrows);
    scan1_kernel<<<nsb, 1024, 0, stream>>>(counts, offsets, bsum, nsegP);
    scan2_prep_kernel<<<2, 1024, 0, stream>>>(bsum, nsb, W1, W2, wbuf);
    scan3_kernel<<<nsb, 1024, 0, stream>>>(offsets, bsum, nsegP, nrows);
    pos_kernel<<<1024, 256, 0, stream>>>(sidx, offsets, ranks, nrows);
    mlp_pred_kernel<<<2048, 256, 0, stream>>>(vecs, ranks, wbuf, b1, b2, preds, nrows);
    seg_reduce_kernel<<<nblk, 256, 0, stream>>>(preds, offsets, out, nseg);
}